// Round 10
// baseline (2823.468 us; speedup 1.0000x reference)
//
#include <hip/hip_runtime.h>
#include <stdint.h>

#define BATCH   4096
#define KDIM    4096      // 2*2048 encode contraction
#define FDIM    16384
#define DDIM    4096
#define TOPK    64

typedef _Float16 half4v __attribute__((ext_vector_type(4)));
typedef _Float16 half8v __attribute__((ext_vector_type(8)));
typedef float    f32x4  __attribute__((ext_vector_type(4)));

// ---------------------------------------------------------------------------
// Encode: C = relu(A @ B + bias), split-A f16x2 MFMA (2 products: hh + lh).
// A = Ah + Al (exact to 22 bits); B rounded to single f16 -> error ~N(0,4e-4)
// per element, max ~2.3e-3 — absorbed by the top-k band+f64 refinement.
// Structure: round-7/8/9 validated (bn-major + XCD swizzle, plain stores).
// ---------------------------------------------------------------------------
__global__ __launch_bounds__(256) void encode_mfma(
    const float* __restrict__ A,
    const float* __restrict__ B,
    const float* __restrict__ bias,
    float* __restrict__ C)
{
    __shared__ _Float16 Ah[128 * 32];   // [m][k], chunk-swizzled rows of 64B
    __shared__ _Float16 Al[128 * 32];
    __shared__ _Float16 Bh[128 * 32];   // 8 subtiles [16col][32k], swizzled

    int nwg = gridDim.x;
    int cpx = nwg >> 3;
    int bid = blockIdx.x;
    int wg  = (bid & 7) * cpx + (bid >> 3);

    // bn-major: consecutive wg share one B panel (XCD-local B slices)
    int bm = (wg & 31) << 7;
    int bn = (wg >> 5) << 7;

    int tid  = threadIdx.x;
    int wave = tid >> 6, lane = tid & 63;
    int wr = wave >> 1, wc = wave & 1;          // 2x2 waves of 64x64
    int lrow = lane & 15, lgrp = lane >> 4;

    int colw = tid & 127;     // B staging: column within tile
    int kh   = tid >> 7;      // k-half
    int nbw  = colw >> 4;
    int colb = colw & 15;

    const float* Arow = A + (size_t)bm * KDIM;

    float4 areg[4];
    float  breg[16];
    #pragma unroll
    for (int i = 0; i < 4; ++i) {
        int idx = tid + i * 256;
        areg[i] = *(const float4*)(Arow + (size_t)(idx >> 3) * KDIM + ((idx & 7) << 2));
    }
    #pragma unroll
    for (int kk = 0; kk < 16; ++kk)
        breg[kk] = B[(size_t)(kh * 16 + kk) * FDIM + bn + colw];

    f32x4 zero = {0.0f, 0.0f, 0.0f, 0.0f};
    f32x4 acc[4][4];
    #pragma unroll
    for (int mf = 0; mf < 4; ++mf)
        #pragma unroll
        for (int nf = 0; nf < 4; ++nf) acc[mf][nf] = zero;

    for (int kt = 0; kt < KDIM; kt += 32) {
        __syncthreads();

        #pragma unroll
        for (int i = 0; i < 4; ++i) {
            int idx = tid + i * 256;
            int m   = idx >> 3;
            int g   = (idx & 7) >> 1;
            int hf  = (idx & 1) << 2;
            int off = m * 32 + ((g ^ ((m >> 1) & 3)) << 3) + hf;
            float v[4] = {areg[i].x, areg[i].y, areg[i].z, areg[i].w};
            half4v h1, h2;
            #pragma unroll
            for (int j = 0; j < 4; ++j) {
                _Float16 h = (_Float16)v[j];
                h1[j] = h;
                h2[j] = (_Float16)(v[j] - (float)h);
            }
            *(half4v*)&Ah[off] = h1;
            *(half4v*)&Al[off] = h2;
        }
        {
            half8v g0h, g1h;
            #pragma unroll
            for (int kk = 0; kk < 8; ++kk) {
                g0h[kk] = (_Float16)breg[kk];
                g1h[kk] = (_Float16)breg[8 + kk];
            }
            int g0 = kh * 2, g1 = kh * 2 + 1;
            int off0 = nbw * 512 + ((colb * 4 + (g0 ^ ((colb >> 1) & 3))) << 3);
            int off1 = nbw * 512 + ((colb * 4 + (g1 ^ ((colb >> 1) & 3))) << 3);
            *(half8v*)&Bh[off0] = g0h;
            *(half8v*)&Bh[off1] = g1h;
        }
        __syncthreads();

        if (kt + 32 < KDIM) {
            #pragma unroll
            for (int i = 0; i < 4; ++i) {
                int idx = tid + i * 256;
                areg[i] = *(const float4*)(Arow + (size_t)(idx >> 3) * KDIM + kt + 32 + ((idx & 7) << 2));
            }
            #pragma unroll
            for (int kk = 0; kk < 16; ++kk)
                breg[kk] = B[(size_t)(kt + 32 + kh * 16 + kk) * FDIM + bn + colw];
        }

        half8v ahf[4], alf[4], bhf[4];
        #pragma unroll
        for (int mf = 0; mf < 4; ++mf) {
            int m   = wr * 64 + mf * 16 + lrow;
            int off = m * 32 + ((lgrp ^ ((m >> 1) & 3)) << 3);
            ahf[mf] = *(half8v*)&Ah[off];
            alf[mf] = *(half8v*)&Al[off];
        }
        #pragma unroll
        for (int nf = 0; nf < 4; ++nf) {
            int nb  = wc * 4 + nf;
            int off = nb * 512 + ((lrow * 4 + (lgrp ^ ((lrow >> 1) & 3))) << 3);
            bhf[nf] = *(half8v*)&Bh[off];
        }

        #pragma unroll
        for (int mf = 0; mf < 4; ++mf)
            #pragma unroll
            for (int nf = 0; nf < 4; ++nf) {
                acc[mf][nf] = __builtin_amdgcn_mfma_f32_16x16x32_f16(ahf[mf], bhf[nf], acc[mf][nf], 0, 0, 0);
                acc[mf][nf] = __builtin_amdgcn_mfma_f32_16x16x32_f16(alf[mf], bhf[nf], acc[mf][nf], 0, 0, 0);
            }
    }

    // epilogue: bias + relu (plain stores)
    #pragma unroll
    for (int nf = 0; nf < 4; ++nf) {
        int col = bn + wc * 64 + nf * 16 + lrow;
        float bb = bias[col];
        #pragma unroll
        for (int mf = 0; mf < 4; ++mf) {
            int row0 = bm + wr * 64 + mf * 16 + lgrp * 4;
            #pragma unroll
            for (int r = 0; r < 4; ++r) {
                float v = acc[mf][nf][r] + bb;
                C[(size_t)(row0 + r) * FDIM + col] = (v > 0.0f) ? v : 0.0f;
            }
        }
    }
}

// ---------------------------------------------------------------------------
// Fused top-k + decode (round-9 validated). EPS_BAND widened to 5e-3 to
// cover the split-A encode's f16-rounding error (max ~2.3e-3; 2.2x margin).
// Margin proof is error-scale-free; f64 refinement decides in-band exactly.
// ---------------------------------------------------------------------------
#define EPS_BAND 5e-3f
#define MAXCAND  32
#define LISTCAP  96

__global__ __launch_bounds__(512) void topk_decode(
    float* __restrict__ feat,
    const float* __restrict__ x,      // (BATCH, KDIM)
    const float* __restrict__ Wenc,   // (KDIM, FDIM)
    const float* __restrict__ benc,   // (FDIM)
    const float* __restrict__ Wdec,   // (FDIM, DDIM)
    const float* __restrict__ bdec,   // (DDIM)
    const float* __restrict__ dmask,  // (FDIM, 2)
    float* __restrict__ recon)        // (BATCH, DDIM)
{
    int b   = blockIdx.x;
    int tid = threadIdx.x;
    int wv  = tid >> 6;               // wave 0..7
    float* frow = feat + (size_t)b * FDIM;

    // ---- load row into registers (stride-512: coalesced) ----
    float r[32];
    #pragma unroll
    for (int i = 0; i < 32; ++i) r[i] = frow[tid + i * 512];

    __shared__ uint32_t hist[8][256];
    __shared__ uint32_t scan[256];
    __shared__ uint32_t sh_prefix, sh_rem;
    __shared__ int   s_ncand, s_ndef, s_n;
    __shared__ int   s_cidx[MAXCAND];
    __shared__ float s_cval[MAXCAND];
    __shared__ int   s_sel[MAXCAND];
    __shared__ int   L_idx[LISTCAP];
    __shared__ float L_v0[LISTCAP], L_v1[LISTCAP];
    __shared__ double red[512];
    __shared__ double s_exact[MAXCAND];

    if (tid == 0) { s_ncand = 0; s_ndef = 0; s_n = 0; }

    // ---- radix pass on top byte (exponent) ----
    #pragma unroll
    for (int i = 0; i < 4; ++i) ((uint32_t*)hist)[tid + i * 512] = 0u;
    __syncthreads();
    #pragma unroll
    for (int i = 0; i < 32; ++i) {
        uint32_t u = __float_as_uint(r[i]);
        if (u) atomicAdd(&hist[wv][u >> 24], 1u);   // skip relu zeros
    }
    __syncthreads();
    if (tid < 256) {
        int rb = 255 - tid;
        uint32_t s = 0;
        #pragma unroll
        for (int w = 0; w < 8; ++w) s += hist[w][rb];
        scan[tid] = s;
    }
    __syncthreads();
    #pragma unroll
    for (int ofs = 1; ofs < 256; ofs <<= 1) {
        uint32_t tv = 0;
        if (tid < 256 && tid >= ofs) tv = scan[tid - ofs];
        __syncthreads();
        if (tid < 256) scan[tid] += tv;
        __syncthreads();
    }
    bool small = (scan[255] <= TOPK);   // uniform across block

    uint32_t prefix = 0, rem = TOPK;
    if (!small) {
        if (tid < 256) {
            uint32_t cum  = scan[tid];
            uint32_t prev = (tid == 0) ? 0u : scan[tid - 1];
            if (cum >= rem && prev < rem) {
                sh_prefix = (uint32_t)(255 - tid);
                sh_rem    = rem - prev;
            }
        }
        __syncthreads();
        prefix = sh_prefix;
        rem    = sh_rem;
        __syncthreads();

        // ---- radix passes on bytes 2,1,0: scan REGISTERS only ----
        for (int byt = 2; byt >= 0; --byt) {
            #pragma unroll
            for (int i = 0; i < 4; ++i) ((uint32_t*)hist)[tid + i * 512] = 0u;
            __syncthreads();
            int shift_hi = (byt + 1) * 8;
            #pragma unroll
            for (int i = 0; i < 32; ++i) {
                uint32_t u = __float_as_uint(r[i]);
                if ((u >> shift_hi) == prefix)
                    atomicAdd(&hist[wv][(u >> (byt * 8)) & 255u], 1u);
            }
            __syncthreads();
            if (tid < 256) {
                int rb = 255 - tid;
                uint32_t s = 0;
                #pragma unroll
                for (int w = 0; w < 8; ++w) s += hist[w][rb];
                scan[tid] = s;
            }
            __syncthreads();
            #pragma unroll
            for (int ofs = 1; ofs < 256; ofs <<= 1) {
                uint32_t tv = 0;
                if (tid < 256 && tid >= ofs) tv = scan[tid - ofs];
                __syncthreads();
                if (tid < 256) scan[tid] += tv;
                __syncthreads();
            }
            if (tid < 256) {
                uint32_t cum  = scan[tid];
                uint32_t prev = (tid == 0) ? 0u : scan[tid - 1];
                if (cum >= rem && prev < rem) {
                    sh_prefix = (prefix << 8) | (uint32_t)(255 - tid);
                    sh_rem    = rem - prev;
                }
            }
            __syncthreads();
            prefix = sh_prefix;
            rem    = sh_rem;
            __syncthreads();
        }

        float T  = __uint_as_float(prefix);
        float hi = T + EPS_BAND;
        float lo = T - EPS_BAND;

        // ---- classify from registers; build decode list; write feat ----
        int mydef = 0;
        #pragma unroll
        for (int i = 0; i < 32; ++i) {
            float val = r[i];
            int   f   = tid + i * 512;
            if (val > hi) {
                ++mydef;
                int s = atomicAdd(&s_n, 1);
                if (s < LISTCAP) {
                    L_idx[s] = f;
                    L_v0[s]  = val * dmask[2 * f + 0];
                    L_v1[s]  = val * dmask[2 * f + 1];
                }
            } else if (val >= lo && val > 0.0f) {
                int s = atomicAdd(&s_ncand, 1);
                if (s < MAXCAND) { s_cidx[s] = f; s_cval[s] = val; }
                r[i] = 0.0f;
            } else {
                r[i] = 0.0f;
            }
        }
        atomicAdd(&s_ndef, mydef);
        #pragma unroll
        for (int i = 0; i < 32; ++i) frow[tid + i * 512] = r[i];
        __syncthreads();

        int A    = (s_ncand < MAXCAND) ? s_ncand : MAXCAND;
        int need = TOPK - s_ndef;

        // ---- f64 refinement when band has more members than slots ----
        if (A > need) {
            const float* xr = x + (size_t)b * KDIM;
            for (int c = 0; c < A; ++c) {
                int f = s_cidx[c];
                double s = 0.0;
                #pragma unroll
                for (int i = 0; i < 8; ++i) {
                    int k = tid + i * 512;
                    s += (double)xr[k] * (double)Wenc[(size_t)k * FDIM + f];
                }
                red[tid] = s;
                __syncthreads();
                for (int ofs = 256; ofs > 0; ofs >>= 1) {
                    if (tid < ofs) red[tid] += red[tid + ofs];
                    __syncthreads();
                }
                if (tid == 0) s_exact[c] = red[0] + (double)benc[f];
                __syncthreads();
            }
            if (tid == 0) {
                for (int c = 0; c < A; ++c) s_sel[c] = 0;
                for (int rr = 0; rr < need; ++rr) {
                    int best = -1;
                    for (int c = 0; c < A; ++c) {
                        if (s_sel[c]) continue;
                        if (best < 0 || s_exact[c] > s_exact[best] ||
                            (s_exact[c] == s_exact[best] && s_cidx[c] < s_cidx[best]))
                            best = c;
                    }
                    if (best >= 0) s_sel[best] = 1;
                }
            }
        } else {
            if (tid == 0)
                for (int c = 0; c < A; ++c) s_sel[c] = 1;   // forced: keep all
        }
        __syncthreads();

        // ---- restore selected in-band features; append to decode list ----
        if (tid < A && s_sel[tid]) {
            int   f   = s_cidx[tid];
            float val = s_cval[tid];
            frow[f] = val;
            int s = atomicAdd(&s_n, 1);
            if (s < LISTCAP) {
                L_idx[s] = f;
                L_v0[s]  = val * dmask[2 * f + 0];
                L_v1[s]  = val * dmask[2 * f + 1];
            }
        }
        __syncthreads();
    } else {
        // ---- nz <= 64: row already equals its top-k; just compact ----
        #pragma unroll
        for (int i = 0; i < 32; ++i) {
            float val = r[i];
            if (val != 0.0f) {
                int f = tid + i * 512;
                int s = atomicAdd(&s_n, 1);
                if (s < LISTCAP) {
                    L_idx[s] = f;
                    L_v0[s]  = val * dmask[2 * f + 0];
                    L_v1[s]  = val * dmask[2 * f + 1];
                }
            }
        }
        __syncthreads();
    }

    int n = (s_n < LISTCAP) ? s_n : LISTCAP;

    // ---- decode: recon[b] = sum_f val_f * Wdec_masked[f] + bdec ----
    const float4* b4 = (const float4*)bdec;
    float4 a0 = b4[tid];
    float4 a1 = b4[tid + 512];

    for (int t = 0; t < n; ++t) {
        int f = L_idx[t];
        float s0 = L_v0[t], s1 = L_v1[t];
        const float4* w = (const float4*)(Wdec + (size_t)f * DDIM);
        float4 w0 = w[tid];
        float4 w1 = w[tid + 512];
        a0.x = fmaf(s0, w0.x, a0.x); a0.y = fmaf(s0, w0.y, a0.y);
        a0.z = fmaf(s0, w0.z, a0.z); a0.w = fmaf(s0, w0.w, a0.w);
        a1.x = fmaf(s1, w1.x, a1.x); a1.y = fmaf(s1, w1.y, a1.y);
        a1.z = fmaf(s1, w1.z, a1.z); a1.w = fmaf(s1, w1.w, a1.w);
    }

    float4* out = (float4*)(recon + (size_t)b * DDIM);
    out[tid]       = a0;
    out[tid + 512] = a1;
}

// ---------------------------------------------------------------------------
extern "C" void kernel_launch(void* const* d_in, const int* in_sizes, int n_in,
                              void* d_out, int out_size, void* d_ws, size_t ws_size,
                              hipStream_t stream)
{
    const float* x     = (const float*)d_in[0];
    const float* Wenc  = (const float*)d_in[1];
    const float* benc  = (const float*)d_in[2];
    const float* Wdec  = (const float*)d_in[3];
    const float* bdec  = (const float*)d_in[4];
    const float* dmask = (const float*)d_in[5];

    float* recon = (float*)d_out;
    float* feat  = recon + (size_t)BATCH * DDIM;

    encode_mfma<<<dim3((BATCH / 128) * (FDIM / 128)), 256, 0, stream>>>(x, Wenc, benc, feat);
    topk_decode<<<dim3(BATCH), 512, 0, stream>>>(feat, x, Wenc, benc, Wdec, bdec, dmask, recon);
}

// Round 11
// 2733.587 us; speedup vs baseline: 1.0329x; 1.0329x over previous
//
#include <hip/hip_runtime.h>
#include <stdint.h>

#define BATCH   4096
#define KDIM    4096      // 2*2048 encode contraction
#define FDIM    16384
#define DDIM    4096
#define TOPK    64

typedef _Float16 half4v __attribute__((ext_vector_type(4)));
typedef _Float16 half8v __attribute__((ext_vector_type(8)));
typedef float    f32x4  __attribute__((ext_vector_type(4)));

// ---------------------------------------------------------------------------
// Encode: C = relu(A @ B + bias), split-A f16x2 MFMA (2 products: hh + lh).
// Round-10 validated verbatim (bn-major + XCD swizzle, plain stores).
// ---------------------------------------------------------------------------
__global__ __launch_bounds__(256) void encode_mfma(
    const float* __restrict__ A,
    const float* __restrict__ B,
    const float* __restrict__ bias,
    float* __restrict__ C)
{
    __shared__ _Float16 Ah[128 * 32];   // [m][k], chunk-swizzled rows of 64B
    __shared__ _Float16 Al[128 * 32];
    __shared__ _Float16 Bh[128 * 32];   // 8 subtiles [16col][32k], swizzled

    int nwg = gridDim.x;
    int cpx = nwg >> 3;
    int bid = blockIdx.x;
    int wg  = (bid & 7) * cpx + (bid >> 3);

    // bn-major: consecutive wg share one B panel (XCD-local B slices)
    int bm = (wg & 31) << 7;
    int bn = (wg >> 5) << 7;

    int tid  = threadIdx.x;
    int wave = tid >> 6, lane = tid & 63;
    int wr = wave >> 1, wc = wave & 1;          // 2x2 waves of 64x64
    int lrow = lane & 15, lgrp = lane >> 4;

    int colw = tid & 127;     // B staging: column within tile
    int kh   = tid >> 7;      // k-half
    int nbw  = colw >> 4;
    int colb = colw & 15;

    const float* Arow = A + (size_t)bm * KDIM;

    float4 areg[4];
    float  breg[16];
    #pragma unroll
    for (int i = 0; i < 4; ++i) {
        int idx = tid + i * 256;
        areg[i] = *(const float4*)(Arow + (size_t)(idx >> 3) * KDIM + ((idx & 7) << 2));
    }
    #pragma unroll
    for (int kk = 0; kk < 16; ++kk)
        breg[kk] = B[(size_t)(kh * 16 + kk) * FDIM + bn + colw];

    f32x4 zero = {0.0f, 0.0f, 0.0f, 0.0f};
    f32x4 acc[4][4];
    #pragma unroll
    for (int mf = 0; mf < 4; ++mf)
        #pragma unroll
        for (int nf = 0; nf < 4; ++nf) acc[mf][nf] = zero;

    for (int kt = 0; kt < KDIM; kt += 32) {
        __syncthreads();

        #pragma unroll
        for (int i = 0; i < 4; ++i) {
            int idx = tid + i * 256;
            int m   = idx >> 3;
            int g   = (idx & 7) >> 1;
            int hf  = (idx & 1) << 2;
            int off = m * 32 + ((g ^ ((m >> 1) & 3)) << 3) + hf;
            float v[4] = {areg[i].x, areg[i].y, areg[i].z, areg[i].w};
            half4v h1, h2;
            #pragma unroll
            for (int j = 0; j < 4; ++j) {
                _Float16 h = (_Float16)v[j];
                h1[j] = h;
                h2[j] = (_Float16)(v[j] - (float)h);
            }
            *(half4v*)&Ah[off] = h1;
            *(half4v*)&Al[off] = h2;
        }
        {
            half8v g0h, g1h;
            #pragma unroll
            for (int kk = 0; kk < 8; ++kk) {
                g0h[kk] = (_Float16)breg[kk];
                g1h[kk] = (_Float16)breg[8 + kk];
            }
            int g0 = kh * 2, g1 = kh * 2 + 1;
            int off0 = nbw * 512 + ((colb * 4 + (g0 ^ ((colb >> 1) & 3))) << 3);
            int off1 = nbw * 512 + ((colb * 4 + (g1 ^ ((colb >> 1) & 3))) << 3);
            *(half8v*)&Bh[off0] = g0h;
            *(half8v*)&Bh[off1] = g1h;
        }
        __syncthreads();

        if (kt + 32 < KDIM) {
            #pragma unroll
            for (int i = 0; i < 4; ++i) {
                int idx = tid + i * 256;
                areg[i] = *(const float4*)(Arow + (size_t)(idx >> 3) * KDIM + kt + 32 + ((idx & 7) << 2));
            }
            #pragma unroll
            for (int kk = 0; kk < 16; ++kk)
                breg[kk] = B[(size_t)(kt + 32 + kh * 16 + kk) * FDIM + bn + colw];
        }

        half8v ahf[4], alf[4], bhf[4];
        #pragma unroll
        for (int mf = 0; mf < 4; ++mf) {
            int m   = wr * 64 + mf * 16 + lrow;
            int off = m * 32 + ((lgrp ^ ((m >> 1) & 3)) << 3);
            ahf[mf] = *(half8v*)&Ah[off];
            alf[mf] = *(half8v*)&Al[off];
        }
        #pragma unroll
        for (int nf = 0; nf < 4; ++nf) {
            int nb  = wc * 4 + nf;
            int off = nb * 512 + ((lrow * 4 + (lgrp ^ ((lrow >> 1) & 3))) << 3);
            bhf[nf] = *(half8v*)&Bh[off];
        }

        #pragma unroll
        for (int mf = 0; mf < 4; ++mf)
            #pragma unroll
            for (int nf = 0; nf < 4; ++nf) {
                acc[mf][nf] = __builtin_amdgcn_mfma_f32_16x16x32_f16(ahf[mf], bhf[nf], acc[mf][nf], 0, 0, 0);
                acc[mf][nf] = __builtin_amdgcn_mfma_f32_16x16x32_f16(alf[mf], bhf[nf], acc[mf][nf], 0, 0, 0);
            }
    }

    // epilogue: bias + relu (plain stores)
    #pragma unroll
    for (int nf = 0; nf < 4; ++nf) {
        int col = bn + wc * 64 + nf * 16 + lrow;
        float bb = bias[col];
        #pragma unroll
        for (int mf = 0; mf < 4; ++mf) {
            int row0 = bm + wr * 64 + mf * 16 + lgrp * 4;
            #pragma unroll
            for (int r = 0; r < 4; ++r) {
                float v = acc[mf][nf][r] + bb;
                C[(size_t)(row0 + r) * FDIM + col] = (v > 0.0f) ? v : 0.0f;
            }
        }
    }
}

// ---------------------------------------------------------------------------
// Fused top-k + decode (round-9/10 validated). ONE change: f64 refinement is
// now WAVE-PARALLEL — each wave refines a different candidate (lane sums 64
// k-terms, 6-step __shfl_down f64 reduce, zero block barriers, 8 column
// gathers in flight). Selection/tie-break logic unchanged.
// ---------------------------------------------------------------------------
#define EPS_BAND 5e-3f
#define MAXCAND  32
#define LISTCAP  96

__global__ __launch_bounds__(512) void topk_decode(
    float* __restrict__ feat,
    const float* __restrict__ x,      // (BATCH, KDIM)
    const float* __restrict__ Wenc,   // (KDIM, FDIM)
    const float* __restrict__ benc,   // (FDIM)
    const float* __restrict__ Wdec,   // (FDIM, DDIM)
    const float* __restrict__ bdec,   // (DDIM)
    const float* __restrict__ dmask,  // (FDIM, 2)
    float* __restrict__ recon)        // (BATCH, DDIM)
{
    int b   = blockIdx.x;
    int tid = threadIdx.x;
    int wv  = tid >> 6;               // wave 0..7
    int lane = tid & 63;
    float* frow = feat + (size_t)b * FDIM;

    // ---- load row into registers (stride-512: coalesced) ----
    float r[32];
    #pragma unroll
    for (int i = 0; i < 32; ++i) r[i] = frow[tid + i * 512];

    __shared__ uint32_t hist[8][256];
    __shared__ uint32_t scan[256];
    __shared__ uint32_t sh_prefix, sh_rem;
    __shared__ int   s_ncand, s_ndef, s_n;
    __shared__ int   s_cidx[MAXCAND];
    __shared__ float s_cval[MAXCAND];
    __shared__ int   s_sel[MAXCAND];
    __shared__ int   L_idx[LISTCAP];
    __shared__ float L_v0[LISTCAP], L_v1[LISTCAP];
    __shared__ double s_exact[MAXCAND];

    if (tid == 0) { s_ncand = 0; s_ndef = 0; s_n = 0; }

    // ---- radix pass on top byte (exponent) ----
    #pragma unroll
    for (int i = 0; i < 4; ++i) ((uint32_t*)hist)[tid + i * 512] = 0u;
    __syncthreads();
    #pragma unroll
    for (int i = 0; i < 32; ++i) {
        uint32_t u = __float_as_uint(r[i]);
        if (u) atomicAdd(&hist[wv][u >> 24], 1u);   // skip relu zeros
    }
    __syncthreads();
    if (tid < 256) {
        int rb = 255 - tid;
        uint32_t s = 0;
        #pragma unroll
        for (int w = 0; w < 8; ++w) s += hist[w][rb];
        scan[tid] = s;
    }
    __syncthreads();
    #pragma unroll
    for (int ofs = 1; ofs < 256; ofs <<= 1) {
        uint32_t tv = 0;
        if (tid < 256 && tid >= ofs) tv = scan[tid - ofs];
        __syncthreads();
        if (tid < 256) scan[tid] += tv;
        __syncthreads();
    }
    bool small = (scan[255] <= TOPK);   // uniform across block

    uint32_t prefix = 0, rem = TOPK;
    if (!small) {
        if (tid < 256) {
            uint32_t cum  = scan[tid];
            uint32_t prev = (tid == 0) ? 0u : scan[tid - 1];
            if (cum >= rem && prev < rem) {
                sh_prefix = (uint32_t)(255 - tid);
                sh_rem    = rem - prev;
            }
        }
        __syncthreads();
        prefix = sh_prefix;
        rem    = sh_rem;
        __syncthreads();

        // ---- radix passes on bytes 2,1,0: scan REGISTERS only ----
        for (int byt = 2; byt >= 0; --byt) {
            #pragma unroll
            for (int i = 0; i < 4; ++i) ((uint32_t*)hist)[tid + i * 512] = 0u;
            __syncthreads();
            int shift_hi = (byt + 1) * 8;
            #pragma unroll
            for (int i = 0; i < 32; ++i) {
                uint32_t u = __float_as_uint(r[i]);
                if ((u >> shift_hi) == prefix)
                    atomicAdd(&hist[wv][(u >> (byt * 8)) & 255u], 1u);
            }
            __syncthreads();
            if (tid < 256) {
                int rb = 255 - tid;
                uint32_t s = 0;
                #pragma unroll
                for (int w = 0; w < 8; ++w) s += hist[w][rb];
                scan[tid] = s;
            }
            __syncthreads();
            #pragma unroll
            for (int ofs = 1; ofs < 256; ofs <<= 1) {
                uint32_t tv = 0;
                if (tid < 256 && tid >= ofs) tv = scan[tid - ofs];
                __syncthreads();
                if (tid < 256) scan[tid] += tv;
                __syncthreads();
            }
            if (tid < 256) {
                uint32_t cum  = scan[tid];
                uint32_t prev = (tid == 0) ? 0u : scan[tid - 1];
                if (cum >= rem && prev < rem) {
                    sh_prefix = (prefix << 8) | (uint32_t)(255 - tid);
                    sh_rem    = rem - prev;
                }
            }
            __syncthreads();
            prefix = sh_prefix;
            rem    = sh_rem;
            __syncthreads();
        }

        float T  = __uint_as_float(prefix);
        float hi = T + EPS_BAND;
        float lo = T - EPS_BAND;

        // ---- classify from registers; build decode list; write feat ----
        int mydef = 0;
        #pragma unroll
        for (int i = 0; i < 32; ++i) {
            float val = r[i];
            int   f   = tid + i * 512;
            if (val > hi) {
                ++mydef;
                int s = atomicAdd(&s_n, 1);
                if (s < LISTCAP) {
                    L_idx[s] = f;
                    L_v0[s]  = val * dmask[2 * f + 0];
                    L_v1[s]  = val * dmask[2 * f + 1];
                }
            } else if (val >= lo && val > 0.0f) {
                int s = atomicAdd(&s_ncand, 1);
                if (s < MAXCAND) { s_cidx[s] = f; s_cval[s] = val; }
                r[i] = 0.0f;
            } else {
                r[i] = 0.0f;
            }
        }
        atomicAdd(&s_ndef, mydef);
        #pragma unroll
        for (int i = 0; i < 32; ++i) frow[tid + i * 512] = r[i];
        __syncthreads();

        int A    = (s_ncand < MAXCAND) ? s_ncand : MAXCAND;
        int need = TOPK - s_ndef;

        // ---- f64 refinement: wave-parallel over candidates ----
        if (A > need) {
            const float* xr = x + (size_t)b * KDIM;
            for (int c0 = 0; c0 < A; c0 += 8) {
                int c = c0 + wv;
                if (c < A) {
                    int f = s_cidx[c];
                    double s = 0.0;
                    #pragma unroll 8
                    for (int i = 0; i < 64; ++i) {
                        int k = lane + i * 64;
                        s += (double)xr[k] * (double)Wenc[(size_t)k * FDIM + f];
                    }
                    #pragma unroll
                    for (int ofs = 32; ofs > 0; ofs >>= 1)
                        s += __shfl_down(s, ofs, 64);
                    if (lane == 0) s_exact[c] = s + (double)benc[f];
                }
            }
            __syncthreads();
            if (tid == 0) {
                for (int c = 0; c < A; ++c) s_sel[c] = 0;
                for (int rr = 0; rr < need; ++rr) {
                    int best = -1;
                    for (int c = 0; c < A; ++c) {
                        if (s_sel[c]) continue;
                        if (best < 0 || s_exact[c] > s_exact[best] ||
                            (s_exact[c] == s_exact[best] && s_cidx[c] < s_cidx[best]))
                            best = c;
                    }
                    if (best >= 0) s_sel[best] = 1;
                }
            }
        } else {
            if (tid == 0)
                for (int c = 0; c < A; ++c) s_sel[c] = 1;   // forced: keep all
        }
        __syncthreads();

        // ---- restore selected in-band features; append to decode list ----
        if (tid < A && s_sel[tid]) {
            int   f   = s_cidx[tid];
            float val = s_cval[tid];
            frow[f] = val;
            int s = atomicAdd(&s_n, 1);
            if (s < LISTCAP) {
                L_idx[s] = f;
                L_v0[s]  = val * dmask[2 * f + 0];
                L_v1[s]  = val * dmask[2 * f + 1];
            }
        }
        __syncthreads();
    } else {
        // ---- nz <= 64: row already equals its top-k; just compact ----
        #pragma unroll
        for (int i = 0; i < 32; ++i) {
            float val = r[i];
            if (val != 0.0f) {
                int f = tid + i * 512;
                int s = atomicAdd(&s_n, 1);
                if (s < LISTCAP) {
                    L_idx[s] = f;
                    L_v0[s]  = val * dmask[2 * f + 0];
                    L_v1[s]  = val * dmask[2 * f + 1];
                }
            }
        }
        __syncthreads();
    }

    int n = (s_n < LISTCAP) ? s_n : LISTCAP;

    // ---- decode: recon[b] = sum_f val_f * Wdec_masked[f] + bdec ----
    const float4* b4 = (const float4*)bdec;
    float4 a0 = b4[tid];
    float4 a1 = b4[tid + 512];

    #pragma unroll 4
    for (int t = 0; t < n; ++t) {
        int f = L_idx[t];
        float s0 = L_v0[t], s1 = L_v1[t];
        const float4* w = (const float4*)(Wdec + (size_t)f * DDIM);
        float4 w0 = w[tid];
        float4 w1 = w[tid + 512];
        a0.x = fmaf(s0, w0.x, a0.x); a0.y = fmaf(s0, w0.y, a0.y);
        a0.z = fmaf(s0, w0.z, a0.z); a0.w = fmaf(s0, w0.w, a0.w);
        a1.x = fmaf(s1, w1.x, a1.x); a1.y = fmaf(s1, w1.y, a1.y);
        a1.z = fmaf(s1, w1.z, a1.z); a1.w = fmaf(s1, w1.w, a1.w);
    }

    float4* out = (float4*)(recon + (size_t)b * DDIM);
    out[tid]       = a0;
    out[tid + 512] = a1;
}

// ---------------------------------------------------------------------------
extern "C" void kernel_launch(void* const* d_in, const int* in_sizes, int n_in,
                              void* d_out, int out_size, void* d_ws, size_t ws_size,
                              hipStream_t stream)
{
    const float* x     = (const float*)d_in[0];
    const float* Wenc  = (const float*)d_in[1];
    const float* benc  = (const float*)d_in[2];
    const float* Wdec  = (const float*)d_in[3];
    const float* bdec  = (const float*)d_in[4];
    const float* dmask = (const float*)d_in[5];

    float* recon = (float*)d_out;
    float* feat  = recon + (size_t)BATCH * DDIM;

    encode_mfma<<<dim3((BATCH / 128) * (FDIM / 128)), 256, 0, stream>>>(x, Wenc, benc, feat);
    topk_decode<<<dim3(BATCH), 512, 0, stream>>>(feat, x, Wenc, benc, Wdec, bdec, dmask, recon);
}

// Round 12
// 2672.443 us; speedup vs baseline: 1.0565x; 1.0229x over previous
//
#include <hip/hip_runtime.h>
#include <stdint.h>

#define BATCH   4096
#define KDIM    4096      // 2*2048 encode contraction
#define FDIM    16384
#define DDIM    4096
#define TOPK    64

typedef _Float16 half4v __attribute__((ext_vector_type(4)));
typedef _Float16 half8v __attribute__((ext_vector_type(8)));
typedef float    f32x4  __attribute__((ext_vector_type(4)));

// ---------------------------------------------------------------------------
// Encode: C = relu(A @ B + bias), split-A f16x2 MFMA (2 products: hh + lh).
// Round-10/11 validated verbatim (bn-major + XCD swizzle, plain stores).
// ---------------------------------------------------------------------------
__global__ __launch_bounds__(256) void encode_mfma(
    const float* __restrict__ A,
    const float* __restrict__ B,
    const float* __restrict__ bias,
    float* __restrict__ C)
{
    __shared__ _Float16 Ah[128 * 32];   // [m][k], chunk-swizzled rows of 64B
    __shared__ _Float16 Al[128 * 32];
    __shared__ _Float16 Bh[128 * 32];   // 8 subtiles [16col][32k], swizzled

    int nwg = gridDim.x;
    int cpx = nwg >> 3;
    int bid = blockIdx.x;
    int wg  = (bid & 7) * cpx + (bid >> 3);

    // bn-major: consecutive wg share one B panel (XCD-local B slices)
    int bm = (wg & 31) << 7;
    int bn = (wg >> 5) << 7;

    int tid  = threadIdx.x;
    int wave = tid >> 6, lane = tid & 63;
    int wr = wave >> 1, wc = wave & 1;          // 2x2 waves of 64x64
    int lrow = lane & 15, lgrp = lane >> 4;

    int colw = tid & 127;     // B staging: column within tile
    int kh   = tid >> 7;      // k-half
    int nbw  = colw >> 4;
    int colb = colw & 15;

    const float* Arow = A + (size_t)bm * KDIM;

    float4 areg[4];
    float  breg[16];
    #pragma unroll
    for (int i = 0; i < 4; ++i) {
        int idx = tid + i * 256;
        areg[i] = *(const float4*)(Arow + (size_t)(idx >> 3) * KDIM + ((idx & 7) << 2));
    }
    #pragma unroll
    for (int kk = 0; kk < 16; ++kk)
        breg[kk] = B[(size_t)(kh * 16 + kk) * FDIM + bn + colw];

    f32x4 zero = {0.0f, 0.0f, 0.0f, 0.0f};
    f32x4 acc[4][4];
    #pragma unroll
    for (int mf = 0; mf < 4; ++mf)
        #pragma unroll
        for (int nf = 0; nf < 4; ++nf) acc[mf][nf] = zero;

    for (int kt = 0; kt < KDIM; kt += 32) {
        __syncthreads();

        #pragma unroll
        for (int i = 0; i < 4; ++i) {
            int idx = tid + i * 256;
            int m   = idx >> 3;
            int g   = (idx & 7) >> 1;
            int hf  = (idx & 1) << 2;
            int off = m * 32 + ((g ^ ((m >> 1) & 3)) << 3) + hf;
            float v[4] = {areg[i].x, areg[i].y, areg[i].z, areg[i].w};
            half4v h1, h2;
            #pragma unroll
            for (int j = 0; j < 4; ++j) {
                _Float16 h = (_Float16)v[j];
                h1[j] = h;
                h2[j] = (_Float16)(v[j] - (float)h);
            }
            *(half4v*)&Ah[off] = h1;
            *(half4v*)&Al[off] = h2;
        }
        {
            half8v g0h, g1h;
            #pragma unroll
            for (int kk = 0; kk < 8; ++kk) {
                g0h[kk] = (_Float16)breg[kk];
                g1h[kk] = (_Float16)breg[8 + kk];
            }
            int g0 = kh * 2, g1 = kh * 2 + 1;
            int off0 = nbw * 512 + ((colb * 4 + (g0 ^ ((colb >> 1) & 3))) << 3);
            int off1 = nbw * 512 + ((colb * 4 + (g1 ^ ((colb >> 1) & 3))) << 3);
            *(half8v*)&Bh[off0] = g0h;
            *(half8v*)&Bh[off1] = g1h;
        }
        __syncthreads();

        if (kt + 32 < KDIM) {
            #pragma unroll
            for (int i = 0; i < 4; ++i) {
                int idx = tid + i * 256;
                areg[i] = *(const float4*)(Arow + (size_t)(idx >> 3) * KDIM + kt + 32 + ((idx & 7) << 2));
            }
            #pragma unroll
            for (int kk = 0; kk < 16; ++kk)
                breg[kk] = B[(size_t)(kt + 32 + kh * 16 + kk) * FDIM + bn + colw];
        }

        half8v ahf[4], alf[4], bhf[4];
        #pragma unroll
        for (int mf = 0; mf < 4; ++mf) {
            int m   = wr * 64 + mf * 16 + lrow;
            int off = m * 32 + ((lgrp ^ ((m >> 1) & 3)) << 3);
            ahf[mf] = *(half8v*)&Ah[off];
            alf[mf] = *(half8v*)&Al[off];
        }
        #pragma unroll
        for (int nf = 0; nf < 4; ++nf) {
            int nb  = wc * 4 + nf;
            int off = nb * 512 + ((lrow * 4 + (lgrp ^ ((lrow >> 1) & 3))) << 3);
            bhf[nf] = *(half8v*)&Bh[off];
        }

        #pragma unroll
        for (int mf = 0; mf < 4; ++mf)
            #pragma unroll
            for (int nf = 0; nf < 4; ++nf) {
                acc[mf][nf] = __builtin_amdgcn_mfma_f32_16x16x32_f16(ahf[mf], bhf[nf], acc[mf][nf], 0, 0, 0);
                acc[mf][nf] = __builtin_amdgcn_mfma_f32_16x16x32_f16(alf[mf], bhf[nf], acc[mf][nf], 0, 0, 0);
            }
    }

    // epilogue: bias + relu (plain stores)
    #pragma unroll
    for (int nf = 0; nf < 4; ++nf) {
        int col = bn + wc * 64 + nf * 16 + lrow;
        float bb = bias[col];
        #pragma unroll
        for (int mf = 0; mf < 4; ++mf) {
            int row0 = bm + wr * 64 + mf * 16 + lgrp * 4;
            #pragma unroll
            for (int r = 0; r < 4; ++r) {
                float v = acc[mf][nf][r] + bb;
                C[(size_t)(row0 + r) * FDIM + col] = (v > 0.0f) ? v : 0.0f;
            }
        }
    }
}

// ---------------------------------------------------------------------------
// Wdec f32 -> bf16 (RTNE) into workspace. Memory-bound grid-stride copy.
// ---------------------------------------------------------------------------
__device__ inline ushort f2bf(float f) {
    uint32_t u = __float_as_uint(f);
    return (ushort)((u + 0x7fffu + ((u >> 16) & 1u)) >> 16);
}

__global__ __launch_bounds__(256) void wdec_to_bf16(
    const float* __restrict__ Wdec, ushort* __restrict__ Wb)
{
    const size_t total4 = (size_t)FDIM * DDIM / 4;
    size_t stride = (size_t)gridDim.x * blockDim.x;
    for (size_t i = (size_t)blockIdx.x * blockDim.x + threadIdx.x; i < total4; i += stride) {
        float4 v = *(const float4*)(Wdec + i * 4);
        ushort4 o;
        o.x = f2bf(v.x); o.y = f2bf(v.y); o.z = f2bf(v.z); o.w = f2bf(v.w);
        *(ushort4*)(Wb + i * 4) = o;
    }
}

// ---------------------------------------------------------------------------
// Fused top-k + decode (round-11 validated). ONE change: decode gathers
// bf16 Wdec from workspace when available (half the gather bytes); falls
// back to the validated f32 gather when Wb == nullptr.
// ---------------------------------------------------------------------------
#define EPS_BAND 5e-3f
#define MAXCAND  32
#define LISTCAP  96

__global__ __launch_bounds__(512) void topk_decode(
    float* __restrict__ feat,
    const float* __restrict__ x,      // (BATCH, KDIM)
    const float* __restrict__ Wenc,   // (KDIM, FDIM)
    const float* __restrict__ benc,   // (FDIM)
    const float* __restrict__ Wdec,   // (FDIM, DDIM) f32
    const ushort* __restrict__ Wb,    // (FDIM, DDIM) bf16 or nullptr
    const float* __restrict__ bdec,   // (DDIM)
    const float* __restrict__ dmask,  // (FDIM, 2)
    float* __restrict__ recon)        // (BATCH, DDIM)
{
    int b   = blockIdx.x;
    int tid = threadIdx.x;
    int wv  = tid >> 6;               // wave 0..7
    int lane = tid & 63;
    float* frow = feat + (size_t)b * FDIM;

    // ---- load row into registers (stride-512: coalesced) ----
    float r[32];
    #pragma unroll
    for (int i = 0; i < 32; ++i) r[i] = frow[tid + i * 512];

    __shared__ uint32_t hist[8][256];
    __shared__ uint32_t scan[256];
    __shared__ uint32_t sh_prefix, sh_rem;
    __shared__ int   s_ncand, s_ndef, s_n;
    __shared__ int   s_cidx[MAXCAND];
    __shared__ float s_cval[MAXCAND];
    __shared__ int   s_sel[MAXCAND];
    __shared__ int   L_idx[LISTCAP];
    __shared__ float L_v0[LISTCAP], L_v1[LISTCAP];
    __shared__ double s_exact[MAXCAND];

    if (tid == 0) { s_ncand = 0; s_ndef = 0; s_n = 0; }

    // ---- radix pass on top byte (exponent) ----
    #pragma unroll
    for (int i = 0; i < 4; ++i) ((uint32_t*)hist)[tid + i * 512] = 0u;
    __syncthreads();
    #pragma unroll
    for (int i = 0; i < 32; ++i) {
        uint32_t u = __float_as_uint(r[i]);
        if (u) atomicAdd(&hist[wv][u >> 24], 1u);   // skip relu zeros
    }
    __syncthreads();
    if (tid < 256) {
        int rb = 255 - tid;
        uint32_t s = 0;
        #pragma unroll
        for (int w = 0; w < 8; ++w) s += hist[w][rb];
        scan[tid] = s;
    }
    __syncthreads();
    #pragma unroll
    for (int ofs = 1; ofs < 256; ofs <<= 1) {
        uint32_t tv = 0;
        if (tid < 256 && tid >= ofs) tv = scan[tid - ofs];
        __syncthreads();
        if (tid < 256) scan[tid] += tv;
        __syncthreads();
    }
    bool small = (scan[255] <= TOPK);   // uniform across block

    uint32_t prefix = 0, rem = TOPK;
    if (!small) {
        if (tid < 256) {
            uint32_t cum  = scan[tid];
            uint32_t prev = (tid == 0) ? 0u : scan[tid - 1];
            if (cum >= rem && prev < rem) {
                sh_prefix = (uint32_t)(255 - tid);
                sh_rem    = rem - prev;
            }
        }
        __syncthreads();
        prefix = sh_prefix;
        rem    = sh_rem;
        __syncthreads();

        // ---- radix passes on bytes 2,1,0: scan REGISTERS only ----
        for (int byt = 2; byt >= 0; --byt) {
            #pragma unroll
            for (int i = 0; i < 4; ++i) ((uint32_t*)hist)[tid + i * 512] = 0u;
            __syncthreads();
            int shift_hi = (byt + 1) * 8;
            #pragma unroll
            for (int i = 0; i < 32; ++i) {
                uint32_t u = __float_as_uint(r[i]);
                if ((u >> shift_hi) == prefix)
                    atomicAdd(&hist[wv][(u >> (byt * 8)) & 255u], 1u);
            }
            __syncthreads();
            if (tid < 256) {
                int rb = 255 - tid;
                uint32_t s = 0;
                #pragma unroll
                for (int w = 0; w < 8; ++w) s += hist[w][rb];
                scan[tid] = s;
            }
            __syncthreads();
            #pragma unroll
            for (int ofs = 1; ofs < 256; ofs <<= 1) {
                uint32_t tv = 0;
                if (tid < 256 && tid >= ofs) tv = scan[tid - ofs];
                __syncthreads();
                if (tid < 256) scan[tid] += tv;
                __syncthreads();
            }
            if (tid < 256) {
                uint32_t cum  = scan[tid];
                uint32_t prev = (tid == 0) ? 0u : scan[tid - 1];
                if (cum >= rem && prev < rem) {
                    sh_prefix = (prefix << 8) | (uint32_t)(255 - tid);
                    sh_rem    = rem - prev;
                }
            }
            __syncthreads();
            prefix = sh_prefix;
            rem    = sh_rem;
            __syncthreads();
        }

        float T  = __uint_as_float(prefix);
        float hi = T + EPS_BAND;
        float lo = T - EPS_BAND;

        // ---- classify from registers; build decode list; write feat ----
        int mydef = 0;
        #pragma unroll
        for (int i = 0; i < 32; ++i) {
            float val = r[i];
            int   f   = tid + i * 512;
            if (val > hi) {
                ++mydef;
                int s = atomicAdd(&s_n, 1);
                if (s < LISTCAP) {
                    L_idx[s] = f;
                    L_v0[s]  = val * dmask[2 * f + 0];
                    L_v1[s]  = val * dmask[2 * f + 1];
                }
            } else if (val >= lo && val > 0.0f) {
                int s = atomicAdd(&s_ncand, 1);
                if (s < MAXCAND) { s_cidx[s] = f; s_cval[s] = val; }
                r[i] = 0.0f;
            } else {
                r[i] = 0.0f;
            }
        }
        atomicAdd(&s_ndef, mydef);
        #pragma unroll
        for (int i = 0; i < 32; ++i) frow[tid + i * 512] = r[i];
        __syncthreads();

        int A    = (s_ncand < MAXCAND) ? s_ncand : MAXCAND;
        int need = TOPK - s_ndef;

        // ---- f64 refinement: wave-parallel over candidates ----
        if (A > need) {
            const float* xr = x + (size_t)b * KDIM;
            for (int c0 = 0; c0 < A; c0 += 8) {
                int c = c0 + wv;
                if (c < A) {
                    int f = s_cidx[c];
                    double s = 0.0;
                    #pragma unroll 8
                    for (int i = 0; i < 64; ++i) {
                        int k = lane + i * 64;
                        s += (double)xr[k] * (double)Wenc[(size_t)k * FDIM + f];
                    }
                    #pragma unroll
                    for (int ofs = 32; ofs > 0; ofs >>= 1)
                        s += __shfl_down(s, ofs, 64);
                    if (lane == 0) s_exact[c] = s + (double)benc[f];
                }
            }
            __syncthreads();
            if (tid == 0) {
                for (int c = 0; c < A; ++c) s_sel[c] = 0;
                for (int rr = 0; rr < need; ++rr) {
                    int best = -1;
                    for (int c = 0; c < A; ++c) {
                        if (s_sel[c]) continue;
                        if (best < 0 || s_exact[c] > s_exact[best] ||
                            (s_exact[c] == s_exact[best] && s_cidx[c] < s_cidx[best]))
                            best = c;
                    }
                    if (best >= 0) s_sel[best] = 1;
                }
            }
        } else {
            if (tid == 0)
                for (int c = 0; c < A; ++c) s_sel[c] = 1;   // forced: keep all
        }
        __syncthreads();

        // ---- restore selected in-band features; append to decode list ----
        if (tid < A && s_sel[tid]) {
            int   f   = s_cidx[tid];
            float val = s_cval[tid];
            frow[f] = val;
            int s = atomicAdd(&s_n, 1);
            if (s < LISTCAP) {
                L_idx[s] = f;
                L_v0[s]  = val * dmask[2 * f + 0];
                L_v1[s]  = val * dmask[2 * f + 1];
            }
        }
        __syncthreads();
    } else {
        // ---- nz <= 64: row already equals its top-k; just compact ----
        #pragma unroll
        for (int i = 0; i < 32; ++i) {
            float val = r[i];
            if (val != 0.0f) {
                int f = tid + i * 512;
                int s = atomicAdd(&s_n, 1);
                if (s < LISTCAP) {
                    L_idx[s] = f;
                    L_v0[s]  = val * dmask[2 * f + 0];
                    L_v1[s]  = val * dmask[2 * f + 1];
                }
            }
        }
        __syncthreads();
    }

    int n = (s_n < LISTCAP) ? s_n : LISTCAP;

    // ---- decode: recon[b] = sum_f val_f * Wdec_masked[f] + bdec ----
    const float4* b4 = (const float4*)bdec;
    float4 a0 = b4[tid];
    float4 a1 = b4[tid + 512];

    if (Wb != nullptr) {
        // bf16 gather: half the bytes
        #pragma unroll 4
        for (int t = 0; t < n; ++t) {
            int f = L_idx[t];
            float s0 = L_v0[t], s1 = L_v1[t];
            const ushort4* w = (const ushort4*)(Wb + (size_t)f * DDIM);
            ushort4 u0 = w[tid];
            ushort4 u1 = w[tid + 512];
            a0.x = fmaf(s0, __uint_as_float((uint32_t)u0.x << 16), a0.x);
            a0.y = fmaf(s0, __uint_as_float((uint32_t)u0.y << 16), a0.y);
            a0.z = fmaf(s0, __uint_as_float((uint32_t)u0.z << 16), a0.z);
            a0.w = fmaf(s0, __uint_as_float((uint32_t)u0.w << 16), a0.w);
            a1.x = fmaf(s1, __uint_as_float((uint32_t)u1.x << 16), a1.x);
            a1.y = fmaf(s1, __uint_as_float((uint32_t)u1.y << 16), a1.y);
            a1.z = fmaf(s1, __uint_as_float((uint32_t)u1.z << 16), a1.z);
            a1.w = fmaf(s1, __uint_as_float((uint32_t)u1.w << 16), a1.w);
        }
    } else {
        // f32 fallback (round-11 validated)
        #pragma unroll 4
        for (int t = 0; t < n; ++t) {
            int f = L_idx[t];
            float s0 = L_v0[t], s1 = L_v1[t];
            const float4* w = (const float4*)(Wdec + (size_t)f * DDIM);
            float4 w0 = w[tid];
            float4 w1 = w[tid + 512];
            a0.x = fmaf(s0, w0.x, a0.x); a0.y = fmaf(s0, w0.y, a0.y);
            a0.z = fmaf(s0, w0.z, a0.z); a0.w = fmaf(s0, w0.w, a0.w);
            a1.x = fmaf(s1, w1.x, a1.x); a1.y = fmaf(s1, w1.y, a1.y);
            a1.z = fmaf(s1, w1.z, a1.z); a1.w = fmaf(s1, w1.w, a1.w);
        }
    }

    float4* out = (float4*)(recon + (size_t)b * DDIM);
    out[tid]       = a0;
    out[tid + 512] = a1;
}

// ---------------------------------------------------------------------------
extern "C" void kernel_launch(void* const* d_in, const int* in_sizes, int n_in,
                              void* d_out, int out_size, void* d_ws, size_t ws_size,
                              hipStream_t stream)
{
    const float* x     = (const float*)d_in[0];
    const float* Wenc  = (const float*)d_in[1];
    const float* benc  = (const float*)d_in[2];
    const float* Wdec  = (const float*)d_in[3];
    const float* bdec  = (const float*)d_in[4];
    const float* dmask = (const float*)d_in[5];

    float* recon = (float*)d_out;
    float* feat  = recon + (size_t)BATCH * DDIM;

    const size_t need_ws = (size_t)FDIM * DDIM * sizeof(ushort);   // 128 MB
    bool use_bf16 = (ws_size >= need_ws);
    ushort* Wb = use_bf16 ? (ushort*)d_ws : nullptr;

    if (use_bf16)
        wdec_to_bf16<<<dim3(2048), 256, 0, stream>>>(Wdec, Wb);

    encode_mfma<<<dim3((BATCH / 128) * (FDIM / 128)), 256, 0, stream>>>(x, Wenc, benc, feat);
    topk_decode<<<dim3(BATCH), 512, 0, stream>>>(feat, x, Wenc, benc, Wdec, Wb, bdec, dmask, recon);
}